// Round 16
// baseline (1546.005 us; speedup 1.0000x reference)
//
#include <hip/hip_runtime.h>

// ---------------- sizes ----------------
// B=8, N=4096, S=1024, K=16, C1=64, D=512, C2=128
#define EPSBN 1e-5f
#define INVSQ 0.04419417382415922f  // 1/sqrt(512)

// ---------------- ws byte offsets ----------------
#define WS_KNN_IDX   32768u       // 131072*4
#define WS_X1        1048576u     // 131072*64*4 = 33554432 (also x2 in-place)
#define WS_BNP1      34603008u    // 512*128*4
#define WS_BN1S      34865152u
#define WS_BNP2      34865664u    // 1024*256*4
#define WS_BN2S      35914240u
#define WS_A         35915264u
#define WS_B         36046336u
#define WS_QB        36177408u
#define WS_KB        36179456u
#define WS_WC        36181504u
#define WS_G         36312576u
#define WS_ZT        36328960u
#define WS_U         36345344u
#define WS_W         36345600u
#define WS_TB        36345856u
#define WS_CC        36346112u
#define WS_PTS4      36346368u    // 32768*16 = 524288
#define WS_FPSPD     36870656u    // 8*256*16*4 = 131072 (fps dist state)
#define WS_FPSC4     37001728u    // 8*16 (fps center state)

// ---------------- pack: xyz -> (x,y,z,|p|^2), 128 blocks x 256 ----------------
__global__ __launch_bounds__(256) void pack_kernel(const float* __restrict__ xyz,
                                                   float4* __restrict__ pts4) {
  int id = blockIdx.x * 256 + threadIdx.x;  // 0..32767
  float x = xyz[id * 3 + 0], y = xyz[id * 3 + 1], z = xyz[id * 3 + 2];
  float pp = __fadd_rn(__fadd_rn(__fmul_rn(x, x), __fmul_rn(y, y)), __fmul_rn(z, z));
  pts4[id] = make_float4(x, y, z, pp);
}

// ---------------- shared fps chunk body (R9-proven math, 256 iterations) ----------------
#define FPS_REDSTEP(CTRL)                                                              \
  {                                                                                    \
    unsigned lo2 = (unsigned)__builtin_amdgcn_update_dpp(0, (int)klo, CTRL, 0xF, 0xF, true); \
    unsigned hi2 = (unsigned)__builtin_amdgcn_update_dpp(0, (int)khi, CTRL, 0xF, 0xF, true); \
    bool tk = (hi2 > khi) || (hi2 == khi && lo2 > klo);                                \
    khi = tk ? hi2 : khi; klo = tk ? lo2 : klo;                                        \
  }

// smem layout for fps role: spts @0 (65536 B), cent @65536 (4096 B), red @69632 (64 B)
__device__ __forceinline__ void fps_chunk_body(unsigned char* smem, const float4* __restrict__ pts4,
                                               float* __restrict__ out_xyz,
                                               float* __restrict__ fps_pd,
                                               float4* __restrict__ fps_c4,
                                               int it0, int b, int t) {
  float4* spts = reinterpret_cast<float4*>(smem);
  float4* cent = reinterpret_cast<float4*>(smem + 65536);
  unsigned long long* red = reinterpret_cast<unsigned long long*>(smem + 69632);  // [2][4]
  const int lane = t & 63, wid = t >> 6;
  const float4* pb = pts4 + (size_t)b * 4096;
  float px[16], py[16], pz[16], pd[16];
  if (it0 == 0) {
#pragma unroll
    for (int i = 0; i < 16; ++i) {
      int j = i * 256 + t;
      float4 p = pb[j];
      spts[j] = p;
      px[i] = p.x; py[i] = p.y; pz[i] = p.z; pd[i] = 1e10f;
    }
  } else {
#pragma unroll
    for (int i = 0; i < 16; ++i) {
      int j = i * 256 + t;
      float4 p = pb[j];
      spts[j] = p;
      px[i] = p.x; py[i] = p.y; pz[i] = p.z;
      pd[i] = fps_pd[i * 2048 + b * 256 + t];
    }
  }
  __syncthreads();
  float4 c4 = (it0 == 0) ? spts[0] : fps_c4[b];
  for (int it = it0; it < it0 + 256; ++it) {
    if (t == 0) cent[it - it0] = c4;
    float bv = -1.0f; int bj = 0;
#pragma unroll
    for (int i = 0; i < 16; ++i) {
      float dx = __fsub_rn(px[i], c4.x);
      float dy = __fsub_rn(py[i], c4.y);
      float dz = __fsub_rn(pz[i], c4.z);
      float d = __fadd_rn(__fadd_rn(__fmul_rn(dx, dx), __fmul_rn(dy, dy)), __fmul_rn(dz, dz));
      float nd = fminf(pd[i], d);
      pd[i] = nd;
      bool g = nd > bv;
      bv = g ? nd : bv;
      bj = g ? (i * 256 + t) : bj;
    }
    unsigned klo = 4095u - (unsigned)bj;
    unsigned khi = __float_as_uint(bv);
    FPS_REDSTEP(0x111)
    FPS_REDSTEP(0x112)
    FPS_REDSTEP(0x114)
    FPS_REDSTEP(0x118)
    FPS_REDSTEP(0x142)
    FPS_REDSTEP(0x143)
    unsigned wlo = (unsigned)__builtin_amdgcn_readlane((int)klo, 63);
    unsigned whi = (unsigned)__builtin_amdgcn_readlane((int)khi, 63);
    const int par = it & 1;
    if (lane == 0) red[par * 4 + wid] = (((unsigned long long)whi) << 32) | wlo;
    __syncthreads();
    const ulonglong2* r2 = reinterpret_cast<const ulonglong2*>(&red[par * 4]);
    ulonglong2 ka = r2[0];
    ulonglong2 kb2 = r2[1];
    unsigned long long m0 = (ka.x > ka.y) ? ka.x : ka.y;
    unsigned long long m1 = (kb2.x > kb2.y) ? kb2.x : kb2.y;
    unsigned long long k0 = (m0 > m1) ? m0 : m1;
    int jw = 4095 - (int)(unsigned)(k0 & 0xFFFFFFFFull);
    c4 = spts[jw];
  }
  // save state
#pragma unroll
  for (int i = 0; i < 16; ++i) fps_pd[i * 2048 + b * 256 + t] = pd[i];
  if (t == 0) fps_c4[b] = c4;
  __syncthreads();
  // copy out this chunk's 256 centers
  for (int o = t; o < 768; o += 256) {
    int j = o / 3;
    int c = o - 3 * j;
    out_xyz[(size_t)b * 3072 + (size_t)it0 * 3 + o] = (&cent[j].x)[c];
  }
}

// ---------------- unified pipeline kernel ----------------
// Roles by block ranges (role disabled when its arg < 0):
//   fps (8 blocks) | knn (512) | mlp1 (128) | prep (prep_mode: 1=combines 384, 2=prep2 34)
// LDS padded to 82048 B (> 160KB/2): ONE block per CU -> fps blocks own their CU
// exclusively (no knn/mlp1 issue-slot interference on the fps latency chain).
__global__ __launch_bounds__(256) void pipe_kernel(
    const float4* __restrict__ pts4, float* __restrict__ out_xyz,
    float* __restrict__ fps_pd, float4* __restrict__ fps_c4,
    int it0, int knn_c0, int mlp_c0, int prep_mode,
    int* __restrict__ knn_idx,
    const float* __restrict__ feat, const float* __restrict__ w1,
    const float* __restrict__ b1, float* __restrict__ x1, float* __restrict__ bnp1,
    const float* __restrict__ wq, const float* __restrict__ wk,
    const float* __restrict__ fc1w, const float* __restrict__ fc1b,
    const float* __restrict__ fc2w, const float* __restrict__ wv,
    const float* __restrict__ fc2b,
    float* __restrict__ A, float* __restrict__ B,
    float* __restrict__ qb, float* __restrict__ kb, float* __restrict__ Wc,
    float* __restrict__ G, float* __restrict__ u, float* __restrict__ w,
    float* __restrict__ cc, float* __restrict__ ZT, float* __restrict__ tb) {
  __shared__ __align__(16) unsigned char smem[82048];
  const int t = threadIdx.x;
  int base = 0;
  if (it0 >= 0) {
    if (blockIdx.x < 8) {
      fps_chunk_body(smem, pts4, out_xyz, fps_pd, fps_c4, it0, blockIdx.x, t);
      return;
    }
    base = 8;
  }
  if (knn_c0 >= 0) {
    if ((int)blockIdx.x < base + 512) {
      // ---- kNN role: one wave per center, centers [knn_c0, knn_c0+256) per batch ----
      const int blk = blockIdx.x - base;
      const int lane = t & 63;
      const int wv2 = (blk << 2) | (t >> 6);        // 0..2047
      const int b = wv2 >> 8;
      const int center = b * 1024 + knn_c0 + (wv2 & 255);
      const float4* P = pts4 + (size_t)b * 4096;
      const float cx = out_xyz[(size_t)center * 3 + 0];
      const float cy = out_xyz[(size_t)center * 3 + 1];
      const float cz = out_xyz[(size_t)center * 3 + 2];
      const float cc2 = __fadd_rn(__fadd_rn(__fmul_rn(cx, cx), __fmul_rn(cy, cy)), __fmul_rn(cz, cz));
      float ldd[16]; int ldi[16];
#pragma unroll
      for (int q = 0; q < 16; ++q) { ldd[q] = 3.4e38f; ldi[q] = 0x7fffffff; }
      for (int i = 0; i < 64; ++i) {
        int j = i * 64 + lane;
        float4 p = P[j];
        float dot = __fadd_rn(__fadd_rn(__fmul_rn(cx, p.x), __fmul_rn(cy, p.y)), __fmul_rn(cz, p.z));
        float d = __fsub_rn(__fadd_rn(cc2, p.w), __fmul_rn(2.0f, dot));
        if (d < ldd[15] || (d == ldd[15] && j < ldi[15])) {
          float cd = d; int ci = j;
#pragma unroll
          for (int q = 0; q < 16; ++q) {
            bool sw = (cd < ldd[q]) || (cd == ldd[q] && ci < ldi[q]);
            float td = ldd[q]; int ti = ldi[q];
            if (sw) { ldd[q] = cd; ldi[q] = ci; cd = td; ci = ti; }
          }
        }
      }
      float cd = ldd[0]; int ci = ldi[0];
      int* op = knn_idx + (size_t)center * 16;
#pragma unroll 1
      for (int k = 0; k < 16; ++k) {
        float wd = cd; int wi = ci;
#pragma unroll
        for (int off = 1; off < 64; off <<= 1) {
          float ov = __shfl_xor(wd, off);
          int   oi = __shfl_xor(wi, off);
          bool tk = (ov < wd) || (ov == wd && oi < wi);
          wd = tk ? ov : wd; wi = tk ? oi : wi;
        }
        if (lane == 0) op[k] = wi;
        if (wd == cd && wi == ci) {
#pragma unroll
          for (int q = 0; q < 15; ++q) { ldd[q] = ldd[q + 1]; ldi[q] = ldi[q + 1]; }
          ldd[15] = 3.4e38f; ldi[15] = 0x7fffffff;
        }
        cd = ldd[0]; ci = ldi[0];
      }
      return;
    }
    base += 512;
  }
  if (mlp_c0 >= 0) {
    if ((int)blockIdx.x < base + 128) {
      // ---- mlp1 role: 128 blocks, 256 contiguous positions each ----
      const int blk = blockIdx.x - base;          // 0..127
      float* w1s = reinterpret_cast<float*>(smem);            // 16384 B
      float* b1s = reinterpret_cast<float*>(smem + 16384);    // 256 B
      float (*ls)[64] = reinterpret_cast<float(*)[64]>(smem + 16640);
      float (*lq)[64] = reinterpret_cast<float(*)[64]>(smem + 17664);
      for (int i = t; i < 4096; i += 256) w1s[i] = w1[i];
      if (t < 64) b1s[t] = b1[t];
      __syncthreads();
      const int batch = blk >> 4;
      const size_t pbase = ((size_t)batch * 1024 + mlp_c0 + (blk & 15) * 16) * 16;
      const size_t pos = pbase + t;
      const int n = knn_idx[pos];
      const float4* fp = reinterpret_cast<const float4*>(feat + ((size_t)(batch * 4096 + n)) * 64);
      float4 fr[16];
#pragma unroll
      for (int i = 0; i < 16; ++i) fr[i] = fp[i];
      float4* op = reinterpret_cast<float4*>(x1 + pos * 64);
#pragma unroll
      for (int cq = 0; cq < 16; ++cq) {
        float a0 = b1s[cq * 4 + 0], a1 = b1s[cq * 4 + 1], a2 = b1s[cq * 4 + 2], a3 = b1s[cq * 4 + 3];
#pragma unroll
        for (int iq = 0; iq < 16; ++iq) {
          float4 f4 = fr[iq];
          float4 wa = *reinterpret_cast<const float4*>(&w1s[(cq * 4 + 0) * 64 + iq * 4]);
          float4 wb = *reinterpret_cast<const float4*>(&w1s[(cq * 4 + 1) * 64 + iq * 4]);
          float4 wc = *reinterpret_cast<const float4*>(&w1s[(cq * 4 + 2) * 64 + iq * 4]);
          float4 wd = *reinterpret_cast<const float4*>(&w1s[(cq * 4 + 3) * 64 + iq * 4]);
          a0 += f4.x * wa.x + f4.y * wa.y + f4.z * wa.z + f4.w * wa.w;
          a1 += f4.x * wb.x + f4.y * wb.y + f4.z * wb.z + f4.w * wb.w;
          a2 += f4.x * wc.x + f4.y * wc.y + f4.z * wc.z + f4.w * wc.w;
          a3 += f4.x * wd.x + f4.y * wd.y + f4.z * wd.z + f4.w * wd.w;
        }
        op[cq] = make_float4(a0, a1, a2, a3);
      }
      __threadfence_block();
      __syncthreads();
      {
        const int c2 = t & 63, g = t >> 6;
        const float* p = x1 + (pbase + g * 64) * 64 + c2;
        float s = 0.f, s2 = 0.f;
        for (int i = 0; i < 64; ++i) { float v = p[(size_t)i * 64]; s += v; s2 = fmaf(v, v, s2); }
        ls[g][c2] = s; lq[g][c2] = s2;
      }
      __syncthreads();
      if (t < 64) {
        const int slot = (mlp_c0 >> 8) * 128 + blk;
        bnp1[slot * 128 + t]      = ls[0][t] + ls[1][t] + ls[2][t] + ls[3][t];
        bnp1[slot * 128 + 64 + t] = lq[0][t] + lq[1][t] + lq[2][t] + lq[3][t];
      }
      return;
    }
    base += 128;
  }
  // ---- prep roles ----
  if (prep_mode == 1) {
    // weight combines: 384 blocks (256 AB + 128 Wc)
    const int blk = blockIdx.x - base;
    if (blk < 256) {
      int id = blk * 256 + t;
      int which = id >> 15;
      int rem = id & 32767;
      int r = rem >> 6, i = rem & 63;
      const float* W = which ? wk : wq;
      float s = 0.f;
      for (int d = 0; d < 512; ++d) s = fmaf(W[r * 512 + d], fc1w[d * 64 + i], s);
      (which ? B : A)[r * 64 + i] = s;
      if (i == 0) {
        float sb = 0.f;
        for (int d = 0; d < 512; ++d) sb = fmaf(W[r * 512 + d], fc1b[d], sb);
        (which ? kb : qb)[r] = sb;
      }
    } else {
      int id = (blk - 256) * 256 + t;
      int c = id >> 9, d = id & 511;
      float s = 0.f;
      for (int e = 0; e < 512; ++e) s = fmaf(fc2w[c * 512 + e], wv[e * 512 + d], s);
      Wc[c * 512 + d] = s;
    }
  } else if (prep_mode == 2) {
    // prep2: 34 blocks (17 G/u/w/cc + 17 ZT/tb)
    const int blk = blockIdx.x - base;
    if (blk < 17) {
      int id = blk * 256 + t;
      if (id < 4096) {
        int i = id >> 6, j = id & 63;
        float s = 0.f;
        for (int d = 0; d < 512; ++d) s = fmaf(A[d * 64 + i], B[d * 64 + j], s);
        G[i * 64 + j] = s * INVSQ;
      } else if (id < 4160) {
        int i = id - 4096; float s = 0.f;
        for (int d = 0; d < 512; ++d) s = fmaf(A[d * 64 + i], kb[d], s);
        u[i] = s * INVSQ;
      } else if (id < 4224) {
        int j = id - 4160; float s = 0.f;
        for (int d = 0; d < 512; ++d) s = fmaf(B[d * 64 + j], qb[d], s);
        w[j] = s * INVSQ;
      } else if (id == 4224) {
        float s = 0.f;
        for (int d = 0; d < 512; ++d) s = fmaf(qb[d], kb[d], s);
        cc[0] = s * INVSQ;
      }
    } else {
      int id = (blk - 17) * 256 + t;
      if (id < 4096) {
        int i = id >> 6, c = id & 63;
        float s = 0.f;
        for (int d = 0; d < 512; ++d) s = fmaf(Wc[c * 512 + d], fc1w[d * 64 + i], s);
        ZT[i * 64 + c] = s;
      } else if (id < 4160) {
        int c = id - 4096; float s = 0.f;
        for (int d = 0; d < 512; ++d) s = fmaf(Wc[c * 512 + d], fc1b[d], s);
        tb[c] = s + fc2b[c];
      }
    }
  }
}

// ---------------- bn1_final: 1 block x 256 ----------------
__global__ __launch_bounds__(256) void bn1_final_kernel(const float* __restrict__ bnp1,
                                                        const float* __restrict__ g1,
                                                        const float* __restrict__ bt1,
                                                        float* __restrict__ bn1s) {
  __shared__ float rs[4][64], rq[4][64];
  const int t = threadIdx.x, c = t & 63, g = t >> 6;
  float S = 0.f, Q = 0.f;
  for (int i = g * 128; i < g * 128 + 128; ++i) {
    S += bnp1[i * 128 + c];
    Q += bnp1[i * 128 + 64 + c];
  }
  rs[g][c] = S; rq[g][c] = Q;
  __syncthreads();
  if (t < 64) {
    float Sa = rs[0][t] + rs[1][t] + rs[2][t] + rs[3][t];
    float Qa = rq[0][t] + rq[1][t] + rq[2][t] + rq[3][t];
    float m = Sa * (1.0f / 131072.0f);
    float var = Qa * (1.0f / 131072.0f) - m * m;
    float sc = g1[t] * rsqrtf(var + EPSBN);
    bn1s[t] = sc;
    bn1s[64 + t] = bt1[t] - m * sc;
  }
}

// ---------------- fused transformer (rank-64 collapsed): 8192 blocks x 64 ----------------
__global__ __launch_bounds__(64) void transformer_fused(
    float* __restrict__ x1, const float* __restrict__ bn1s,
    const float* __restrict__ G, const float* __restrict__ u, const float* __restrict__ w,
    const float* __restrict__ cc, const float* __restrict__ ZT, const float* __restrict__ tb) {
  __shared__ float pre[16][65];
  __shared__ float ts[16][65];
  __shared__ float ys[16][65];
  __shared__ float ss[16][17];
  __shared__ float spu[16], spw[16];
  const int c = threadIdx.x;
  const size_t base = (size_t)blockIdx.x * 1024;
  const float sc = bn1s[c], sh = bn1s[64 + c];
  float pc[16];
#pragma unroll
  for (int k = 0; k < 16; ++k) {
    float v = x1[base + k * 64 + c];
    float p = fmaxf(0.f, v * sc + sh);
    pc[k] = p; pre[k][c] = p;
  }
  __syncthreads();
  float tcol[16], ycol[16];
#pragma unroll
  for (int k = 0; k < 16; ++k) { tcol[k] = 0.f; ycol[k] = 0.f; }
  for (int i = 0; i < 64; ++i) {
    float g = G[i * 64 + c];
    float z = ZT[i * 64 + c];
#pragma unroll
    for (int k = 0; k < 16; ++k) {
      float p = pre[k][i];
      tcol[k] = fmaf(p, g, tcol[k]);
      ycol[k] = fmaf(p, z, ycol[k]);
    }
  }
#pragma unroll
  for (int k = 0; k < 16; ++k) { ts[k][c] = tcol[k]; ys[k][c] = ycol[k]; }
  if (c < 16) {
    float s = 0.f;
    for (int i = 0; i < 64; ++i) s = fmaf(pre[c][i], u[i], s);
    spu[c] = s;
  } else if (c < 32) {
    int m = c - 16; float s = 0.f;
    for (int i = 0; i < 64; ++i) s = fmaf(pre[m][i], w[i], s);
    spw[m] = s;
  }
  __syncthreads();
  {
    const float cval = cc[0];
    const int m = c & 15, nb = c >> 4;
#pragma unroll
    for (int ng = 0; ng < 4; ++ng) {
      int n = ng * 4 + nb;
      float s = 0.f;
      for (int i = 0; i < 64; ++i) s = fmaf(ts[n][i], pre[m][i], s);
      ss[n][m] = s + spu[n] + spw[m] + cval;
    }
  }
  __syncthreads();
  if (c < 16) {
    float mx = -3.4e38f;
#pragma unroll
    for (int m = 0; m < 16; ++m) mx = fmaxf(mx, ss[c][m]);
    float e[16], sum = 0.f;
#pragma unroll
    for (int m = 0; m < 16; ++m) { e[m] = expf(ss[c][m] - mx); sum += e[m]; }
    float r = 1.0f / sum;
#pragma unroll
    for (int m = 0; m < 16; ++m) ss[c][m] = e[m] * r;
  }
  __syncthreads();
  const float tbc = tb[c];
  float o[16];
#pragma unroll
  for (int k = 0; k < 16; ++k) o[k] = 0.f;
#pragma unroll
  for (int m = 0; m < 16; ++m) {
    float yv = ys[m][c];
#pragma unroll
    for (int k = 0; k < 16; ++k) o[k] = fmaf(ss[k][m], yv, o[k]);
  }
#pragma unroll
  for (int k = 0; k < 16; ++k) x1[base + k * 64 + c] = o[k] + tbc + pc[k];
}

// ---------------- BN2 stats + raw pooled max (monotone BN): 1024 blocks x 256 ----------------
__global__ __launch_bounds__(256) void bn2_stats_kernel(const float* __restrict__ x2,
                                                        const float* __restrict__ w2,
                                                        const float* __restrict__ b2,
                                                        float* __restrict__ bnp2,
                                                        float* __restrict__ out) {
  __shared__ float sx2[128 * 64];
  __shared__ float ps[2][128], pq[2][128];
  const int t = threadIdx.x;
  const float4* s4 = reinterpret_cast<const float4*>(x2 + (size_t)blockIdx.x * 128 * 64);
  float4* d4 = reinterpret_cast<float4*>(sx2);
  for (int i = 0; i < 8; ++i) d4[i * 256 + t] = s4[i * 256 + t];
  __syncthreads();
  const int c = t & 127, h = t >> 7;
  float4 wreg[16];
  const float4* w4 = reinterpret_cast<const float4*>(w2 + c * 64);
#pragma unroll
  for (int i = 0; i < 16; ++i) wreg[i] = w4[i];
  const float bb = b2[c];
  float s = 0.f, q = 0.f;
  float* omax = out + 24576 + ((size_t)blockIdx.x * 8 + 4 * h) * 128 + c;
#pragma unroll
  for (int gi = 0; gi < 4; ++gi) {
    float mx = -3.4e38f;
#pragma unroll 4
    for (int p2 = 0; p2 < 16; ++p2) {
      const int p = gi * 16 + p2;
      const float4* xr = reinterpret_cast<const float4*>(&sx2[(h * 64 + p) * 64]);
      float acc = bb;
#pragma unroll
      for (int i = 0; i < 16; ++i) {
        float4 xv = xr[i];
        acc += xv.x * wreg[i].x + xv.y * wreg[i].y + xv.z * wreg[i].z + xv.w * wreg[i].w;
      }
      s += acc; q = fmaf(acc, acc, q);
      mx = fmaxf(mx, acc);
    }
    omax[(size_t)gi * 128] = mx;
  }
  ps[h][c] = s; pq[h][c] = q;
  __syncthreads();
  if (t < 128) {
    bnp2[blockIdx.x * 256 + t]       = ps[0][t] + ps[1][t];
    bnp2[blockIdx.x * 256 + 128 + t] = pq[0][t] + pq[1][t];
  }
}

// ---------------- bn2_final: 1 block x 512 ----------------
__global__ __launch_bounds__(512) void bn2_final_kernel(const float* __restrict__ bnp2,
                                                        const float* __restrict__ g2,
                                                        const float* __restrict__ bt2,
                                                        float* __restrict__ bn2s) {
  __shared__ float rs[4][128], rq[4][128];
  const int t = threadIdx.x, c = t & 127, g = t >> 7;
  float S = 0.f, Q = 0.f;
  for (int i = g * 256; i < g * 256 + 256; ++i) {
    S += bnp2[i * 256 + c];
    Q += bnp2[i * 256 + 128 + c];
  }
  rs[g][c] = S; rq[g][c] = Q;
  __syncthreads();
  if (t < 128) {
    float Sa = rs[0][t] + rs[1][t] + rs[2][t] + rs[3][t];
    float Qa = rq[0][t] + rq[1][t] + rq[2][t] + rq[3][t];
    float m = Sa * (1.0f / 131072.0f);
    float var = Qa * (1.0f / 131072.0f) - m * m;
    float sc = g2[t] * rsqrtf(var + EPSBN);
    bn2s[t] = sc;
    bn2s[128 + t] = bt2[t] - m * sc;
  }
}

// ---------------- final: in-place BN+ReLU on pooled maxes: 1024 blocks x 256 ----------------
__global__ __launch_bounds__(256) void final_kernel(const float* __restrict__ bn2s,
                                                    float* __restrict__ out) {
  __shared__ float s_sc[128], s_sh[128];
  const int t = threadIdx.x;
  if (t < 128) { s_sc[t] = bn2s[t]; s_sh[t] = bn2s[128 + t]; }
  __syncthreads();
  const int base = blockIdx.x * 1024 + t;
#pragma unroll
  for (int r = 0; r < 4; ++r) {
    const int i = base + r * 256;
    const int c = i & 127;
    float v = out[24576 + i];
    out[24576 + i] = fmaxf(0.f, v * s_sc[c] + s_sh[c]);
  }
}

// ---------------- launch ----------------
extern "C" void kernel_launch(void* const* d_in, const int* in_sizes, int n_in,
                              void* d_out, int out_size, void* d_ws, size_t ws_size,
                              hipStream_t stream) {
  const float* xyz  = (const float*)d_in[0];
  const float* feat = (const float*)d_in[1];
  const float* w1   = (const float*)d_in[2];
  const float* b1   = (const float*)d_in[3];
  const float* g1   = (const float*)d_in[4];
  const float* bt1  = (const float*)d_in[5];
  const float* fc1w = (const float*)d_in[6];
  const float* fc1b = (const float*)d_in[7];
  const float* wq   = (const float*)d_in[8];
  const float* wk   = (const float*)d_in[9];
  const float* wv   = (const float*)d_in[10];
  const float* fc2w = (const float*)d_in[11];
  const float* fc2b = (const float*)d_in[12];
  const float* w2   = (const float*)d_in[13];
  const float* b2   = (const float*)d_in[14];
  const float* g2   = (const float*)d_in[15];
  const float* bt2  = (const float*)d_in[16];
  float* out = (float*)d_out;
  char* ws = (char*)d_ws;

  int*    knn_idx = (int*)(ws + WS_KNN_IDX);
  float*  x1      = (float*)(ws + WS_X1);
  float*  bnp1    = (float*)(ws + WS_BNP1);
  float*  bn1s    = (float*)(ws + WS_BN1S);
  float*  bnp2    = (float*)(ws + WS_BNP2);
  float*  bn2s    = (float*)(ws + WS_BN2S);
  float*  Abuf    = (float*)(ws + WS_A);
  float*  Bbuf    = (float*)(ws + WS_B);
  float*  qb      = (float*)(ws + WS_QB);
  float*  kb      = (float*)(ws + WS_KB);
  float*  Wc      = (float*)(ws + WS_WC);
  float*  G       = (float*)(ws + WS_G);
  float*  ZT      = (float*)(ws + WS_ZT);
  float*  u       = (float*)(ws + WS_U);
  float*  w       = (float*)(ws + WS_W);
  float*  tb      = (float*)(ws + WS_TB);
  float*  cc      = (float*)(ws + WS_CC);
  float4* pts4    = (float4*)(ws + WS_PTS4);
  float*  fps_pd  = (float*)(ws + WS_FPSPD);
  float4* fps_c4  = (float4*)(ws + WS_FPSC4);

#define PIPE_ARGS pts4, out, fps_pd, fps_c4
#define TAIL_ARGS knn_idx, feat, w1, b1, x1, bnp1, wq, wk, fc1w, fc1b, fc2w, wv, fc2b, \
                  Abuf, Bbuf, qb, kb, Wc, G, u, w, cc, ZT, tb

  pack_kernel<<<128, 256, 0, stream>>>(xyz, pts4);
  // L1: fps chunk0 + weight combines (384)
  pipe_kernel<<<392, 256, 0, stream>>>(PIPE_ARGS, 0, -1, -1, 1, TAIL_ARGS);
  // L2: fps chunk1 + knn[0,256) + prep2 (34)
  pipe_kernel<<<554, 256, 0, stream>>>(PIPE_ARGS, 256, 0, -1, 2, TAIL_ARGS);
  // L3: fps chunk2 + knn[256,512) + mlp1[0,256)
  pipe_kernel<<<648, 256, 0, stream>>>(PIPE_ARGS, 512, 256, 0, 0, TAIL_ARGS);
  // L4: fps chunk3 + knn[512,768) + mlp1[256,512)
  pipe_kernel<<<648, 256, 0, stream>>>(PIPE_ARGS, 768, 512, 256, 0, TAIL_ARGS);
  // L5: knn[768,1024) + mlp1[512,768)
  pipe_kernel<<<640, 256, 0, stream>>>(PIPE_ARGS, -1, 768, 512, 0, TAIL_ARGS);
  // L6: mlp1[768,1024)
  pipe_kernel<<<128, 256, 0, stream>>>(PIPE_ARGS, -1, -1, 768, 0, TAIL_ARGS);
  bn1_final_kernel<<<1, 256, 0, stream>>>(bnp1, g1, bt1, bn1s);
  transformer_fused<<<8192, 64, 0, stream>>>(x1, bn1s, G, u, w, cc, ZT, tb);
  bn2_stats_kernel<<<1024, 256, 0, stream>>>(x1, w2, b2, bnp2, out);
  bn2_final_kernel<<<1, 512, 0, stream>>>(bnp2, g2, bt2, bn2s);
  final_kernel<<<1024, 256, 0, stream>>>(bn2s, out);
#undef PIPE_ARGS
#undef TAIL_ARGS
}

// Round 17
// 1152.571 us; speedup vs baseline: 1.3414x; 1.3414x over previous
//
#include <hip/hip_runtime.h>

// ---------------- sizes ----------------
// B=8, N=4096, S=1024, K=16, C1=64, D=512, C2=128
#define EPSBN 1e-5f
#define INVSQ 0.04419417382415922f  // 1/sqrt(512)

// ---------------- ws byte offsets ----------------
#define WS_KNN_IDX   32768u       // 131072*4
#define WS_X1        1048576u     // 131072*64*4 = 33554432 (also x2 in-place)
#define WS_BNP1      34603008u    // 512*128*4
#define WS_BN1S      34865152u
#define WS_BNP2      34865664u    // 1024*256*4
#define WS_BN2S      35914240u
#define WS_A         35915264u
#define WS_B         36046336u
#define WS_QB        36177408u
#define WS_KB        36179456u
#define WS_WC        36181504u
#define WS_G         36312576u
#define WS_ZT        36328960u
#define WS_U         36345344u
#define WS_W         36345600u
#define WS_TB        36345856u
#define WS_CC        36346112u
#define WS_PTS4      36346368u    // 32768*16 = 524288
#define WS_FPSPD     36870656u    // 8*256*16*4 = 131072 (fps dist state)
#define WS_FPSC4     37001728u    // 8*16 (fps center state)

// ---------------- pack: xyz -> (x,y,z,|p|^2), 128 blocks x 256 ----------------
__global__ __launch_bounds__(256) void pack_kernel(const float* __restrict__ xyz,
                                                   float4* __restrict__ pts4) {
  int id = blockIdx.x * 256 + threadIdx.x;  // 0..32767
  float x = xyz[id * 3 + 0], y = xyz[id * 3 + 1], z = xyz[id * 3 + 2];
  float pp = __fadd_rn(__fadd_rn(__fmul_rn(x, x), __fmul_rn(y, y)), __fmul_rn(z, z));
  pts4[id] = make_float4(x, y, z, pp);
}

// ---------------- shared fps chunk body (R9-proven math, 512 iterations) ----------------
#define FPS_REDSTEP(CTRL)                                                              \
  {                                                                                    \
    unsigned lo2 = (unsigned)__builtin_amdgcn_update_dpp(0, (int)klo, CTRL, 0xF, 0xF, true); \
    unsigned hi2 = (unsigned)__builtin_amdgcn_update_dpp(0, (int)khi, CTRL, 0xF, 0xF, true); \
    bool tk = (hi2 > khi) || (hi2 == khi && lo2 > klo);                                \
    khi = tk ? hi2 : khi; klo = tk ? lo2 : klo;                                        \
  }

// smem layout for fps role: spts @0 (65536 B), cent @65536 (8192 B), red @73728 (64 B)
__device__ __forceinline__ void fps_chunk_body(unsigned char* smem, const float4* __restrict__ pts4,
                                               float* __restrict__ out_xyz,
                                               float* __restrict__ fps_pd,
                                               float4* __restrict__ fps_c4,
                                               int it0, int b, int t) {
  float4* spts = reinterpret_cast<float4*>(smem);
  float4* cent = reinterpret_cast<float4*>(smem + 65536);
  unsigned long long* red = reinterpret_cast<unsigned long long*>(smem + 73728);  // [2][4]
  const int lane = t & 63, wid = t >> 6;
  const float4* pb = pts4 + (size_t)b * 4096;
  float px[16], py[16], pz[16], pd[16];
  if (it0 == 0) {
#pragma unroll
    for (int i = 0; i < 16; ++i) {
      int j = i * 256 + t;
      float4 p = pb[j];
      spts[j] = p;
      px[i] = p.x; py[i] = p.y; pz[i] = p.z; pd[i] = 1e10f;
    }
  } else {
#pragma unroll
    for (int i = 0; i < 16; ++i) {
      int j = i * 256 + t;
      float4 p = pb[j];
      spts[j] = p;
      px[i] = p.x; py[i] = p.y; pz[i] = p.z;
      pd[i] = fps_pd[i * 2048 + b * 256 + t];
    }
  }
  __syncthreads();
  float4 c4 = (it0 == 0) ? spts[0] : fps_c4[b];
  for (int it = it0; it < it0 + 512; ++it) {
    if (t == 0) cent[it - it0] = c4;
    float bv = -1.0f; int bj = 0;
#pragma unroll
    for (int i = 0; i < 16; ++i) {
      float dx = __fsub_rn(px[i], c4.x);
      float dy = __fsub_rn(py[i], c4.y);
      float dz = __fsub_rn(pz[i], c4.z);
      float d = __fadd_rn(__fadd_rn(__fmul_rn(dx, dx), __fmul_rn(dy, dy)), __fmul_rn(dz, dz));
      float nd = fminf(pd[i], d);
      pd[i] = nd;
      bool g = nd > bv;
      bv = g ? nd : bv;
      bj = g ? (i * 256 + t) : bj;
    }
    unsigned klo = 4095u - (unsigned)bj;
    unsigned khi = __float_as_uint(bv);
    FPS_REDSTEP(0x111)
    FPS_REDSTEP(0x112)
    FPS_REDSTEP(0x114)
    FPS_REDSTEP(0x118)
    FPS_REDSTEP(0x142)
    FPS_REDSTEP(0x143)
    unsigned wlo = (unsigned)__builtin_amdgcn_readlane((int)klo, 63);
    unsigned whi = (unsigned)__builtin_amdgcn_readlane((int)khi, 63);
    const int par = it & 1;
    if (lane == 0) red[par * 4 + wid] = (((unsigned long long)whi) << 32) | wlo;
    __syncthreads();
    const ulonglong2* r2 = reinterpret_cast<const ulonglong2*>(&red[par * 4]);
    ulonglong2 ka = r2[0];
    ulonglong2 kb2 = r2[1];
    unsigned long long m0 = (ka.x > ka.y) ? ka.x : ka.y;
    unsigned long long m1 = (kb2.x > kb2.y) ? kb2.x : kb2.y;
    unsigned long long k0 = (m0 > m1) ? m0 : m1;
    int jw = 4095 - (int)(unsigned)(k0 & 0xFFFFFFFFull);
    c4 = spts[jw];
  }
  // save state (needed between chunk0 and chunk1; harmless after chunk1)
#pragma unroll
  for (int i = 0; i < 16; ++i) fps_pd[i * 2048 + b * 256 + t] = pd[i];
  if (t == 0) fps_c4[b] = c4;
  __syncthreads();
  // copy out this chunk's 512 centers
  for (int o = t; o < 1536; o += 256) {
    int j = o / 3;
    int c = o - 3 * j;
    out_xyz[(size_t)b * 3072 + (size_t)it0 * 3 + o] = (&cent[j].x)[c];
  }
}

// ---------------- unified pipeline kernel ----------------
// Roles by block ranges (role disabled when its arg < 0):
//   fps (8 blocks, 512 its) | knn (1024 blocks, 512 centers/batch) |
//   mlp1 (256 blocks, 512 centers/batch) | prep (1=combines 384, 2=prep2 34)
__global__ __launch_bounds__(256) void pipe_kernel(
    const float4* __restrict__ pts4, float* __restrict__ out_xyz,
    float* __restrict__ fps_pd, float4* __restrict__ fps_c4,
    int it0, int knn_c0, int mlp_c0, int prep_mode,
    int* __restrict__ knn_idx,
    const float* __restrict__ feat, const float* __restrict__ w1,
    const float* __restrict__ b1, float* __restrict__ x1, float* __restrict__ bnp1,
    const float* __restrict__ wq, const float* __restrict__ wk,
    const float* __restrict__ fc1w, const float* __restrict__ fc1b,
    const float* __restrict__ fc2w, const float* __restrict__ wv,
    const float* __restrict__ fc2b,
    float* __restrict__ A, float* __restrict__ B,
    float* __restrict__ qb, float* __restrict__ kb, float* __restrict__ Wc,
    float* __restrict__ G, float* __restrict__ u, float* __restrict__ w,
    float* __restrict__ cc, float* __restrict__ ZT, float* __restrict__ tb) {
  __shared__ __align__(16) unsigned char smem[73792];
  const int t = threadIdx.x;
  int base = 0;
  if (it0 >= 0) {
    if (blockIdx.x < 8) {
      fps_chunk_body(smem, pts4, out_xyz, fps_pd, fps_c4, it0, blockIdx.x, t);
      return;
    }
    base = 8;
  }
  if (knn_c0 >= 0) {
    if ((int)blockIdx.x < base + 1024) {
      // ---- kNN role: one wave per center, centers [knn_c0, knn_c0+512) per batch ----
      const int blk = blockIdx.x - base;
      const int lane = t & 63;
      const int wv2 = (blk << 2) | (t >> 6);        // 0..4095
      const int b = wv2 >> 9;
      const int center = b * 1024 + knn_c0 + (wv2 & 511);
      const float4* P = pts4 + (size_t)b * 4096;
      const float cx = out_xyz[(size_t)center * 3 + 0];
      const float cy = out_xyz[(size_t)center * 3 + 1];
      const float cz = out_xyz[(size_t)center * 3 + 2];
      const float cc2 = __fadd_rn(__fadd_rn(__fmul_rn(cx, cx), __fmul_rn(cy, cy)), __fmul_rn(cz, cz));
      float ldd[16]; int ldi[16];
#pragma unroll
      for (int q = 0; q < 16; ++q) { ldd[q] = 3.4e38f; ldi[q] = 0x7fffffff; }
      for (int i = 0; i < 64; ++i) {
        int j = i * 64 + lane;
        float4 p = P[j];
        float dot = __fadd_rn(__fadd_rn(__fmul_rn(cx, p.x), __fmul_rn(cy, p.y)), __fmul_rn(cz, p.z));
        float d = __fsub_rn(__fadd_rn(cc2, p.w), __fmul_rn(2.0f, dot));
        if (d < ldd[15] || (d == ldd[15] && j < ldi[15])) {
          float cd = d; int ci = j;
#pragma unroll
          for (int q = 0; q < 16; ++q) {
            bool sw = (cd < ldd[q]) || (cd == ldd[q] && ci < ldi[q]);
            float td = ldd[q]; int ti = ldi[q];
            if (sw) { ldd[q] = cd; ldi[q] = ci; cd = td; ci = ti; }
          }
        }
      }
      float cd = ldd[0]; int ci = ldi[0];
      int* op = knn_idx + (size_t)center * 16;
#pragma unroll 1
      for (int k = 0; k < 16; ++k) {
        float wd = cd; int wi = ci;
#pragma unroll
        for (int off = 1; off < 64; off <<= 1) {
          float ov = __shfl_xor(wd, off);
          int   oi = __shfl_xor(wi, off);
          bool tk = (ov < wd) || (ov == wd && oi < wi);
          wd = tk ? ov : wd; wi = tk ? oi : wi;
        }
        if (lane == 0) op[k] = wi;
        if (wd == cd && wi == ci) {
#pragma unroll
          for (int q = 0; q < 15; ++q) { ldd[q] = ldd[q + 1]; ldi[q] = ldi[q + 1]; }
          ldd[15] = 3.4e38f; ldi[15] = 0x7fffffff;
        }
        cd = ldd[0]; ci = ldi[0];
      }
      return;
    }
    base += 1024;
  }
  if (mlp_c0 >= 0) {
    if ((int)blockIdx.x < base + 256) {
      // ---- mlp1 role: 256 blocks, 256 contiguous positions each (512 centers/batch) ----
      const int blk = blockIdx.x - base;          // 0..255
      float* w1s = reinterpret_cast<float*>(smem);            // 16384 B
      float* b1s = reinterpret_cast<float*>(smem + 16384);    // 256 B
      float (*ls)[64] = reinterpret_cast<float(*)[64]>(smem + 16640);
      float (*lq)[64] = reinterpret_cast<float(*)[64]>(smem + 17664);
      for (int i = t; i < 4096; i += 256) w1s[i] = w1[i];
      if (t < 64) b1s[t] = b1[t];
      __syncthreads();
      const int batch = blk >> 5;
      const size_t pbase = ((size_t)batch * 1024 + mlp_c0 + (blk & 31) * 16) * 16;
      const size_t pos = pbase + t;
      const int n = knn_idx[pos];
      const float4* fp = reinterpret_cast<const float4*>(feat + ((size_t)(batch * 4096 + n)) * 64);
      float4 fr[16];
#pragma unroll
      for (int i = 0; i < 16; ++i) fr[i] = fp[i];
      float4* op = reinterpret_cast<float4*>(x1 + pos * 64);
#pragma unroll
      for (int cq = 0; cq < 16; ++cq) {
        float a0 = b1s[cq * 4 + 0], a1 = b1s[cq * 4 + 1], a2 = b1s[cq * 4 + 2], a3 = b1s[cq * 4 + 3];
#pragma unroll
        for (int iq = 0; iq < 16; ++iq) {
          float4 f4 = fr[iq];
          float4 wa = *reinterpret_cast<const float4*>(&w1s[(cq * 4 + 0) * 64 + iq * 4]);
          float4 wb = *reinterpret_cast<const float4*>(&w1s[(cq * 4 + 1) * 64 + iq * 4]);
          float4 wc = *reinterpret_cast<const float4*>(&w1s[(cq * 4 + 2) * 64 + iq * 4]);
          float4 wd = *reinterpret_cast<const float4*>(&w1s[(cq * 4 + 3) * 64 + iq * 4]);
          a0 += f4.x * wa.x + f4.y * wa.y + f4.z * wa.z + f4.w * wa.w;
          a1 += f4.x * wb.x + f4.y * wb.y + f4.z * wb.z + f4.w * wb.w;
          a2 += f4.x * wc.x + f4.y * wc.y + f4.z * wc.z + f4.w * wc.w;
          a3 += f4.x * wd.x + f4.y * wd.y + f4.z * wd.z + f4.w * wd.w;
        }
        op[cq] = make_float4(a0, a1, a2, a3);
      }
      __threadfence_block();
      __syncthreads();
      {
        const int c2 = t & 63, g = t >> 6;
        const float* p = x1 + (pbase + g * 64) * 64 + c2;
        float s = 0.f, s2 = 0.f;
        for (int i = 0; i < 64; ++i) { float v = p[(size_t)i * 64]; s += v; s2 = fmaf(v, v, s2); }
        ls[g][c2] = s; lq[g][c2] = s2;
      }
      __syncthreads();
      if (t < 64) {
        const int slot = (mlp_c0 >> 9) * 256 + blk;
        bnp1[slot * 128 + t]      = ls[0][t] + ls[1][t] + ls[2][t] + ls[3][t];
        bnp1[slot * 128 + 64 + t] = lq[0][t] + lq[1][t] + lq[2][t] + lq[3][t];
      }
      return;
    }
    base += 256;
  }
  // ---- prep roles ----
  if (prep_mode == 1) {
    // weight combines: 384 blocks (256 AB + 128 Wc)
    const int blk = blockIdx.x - base;
    if (blk < 256) {
      int id = blk * 256 + t;
      int which = id >> 15;
      int rem = id & 32767;
      int r = rem >> 6, i = rem & 63;
      const float* W = which ? wk : wq;
      float s = 0.f;
      for (int d = 0; d < 512; ++d) s = fmaf(W[r * 512 + d], fc1w[d * 64 + i], s);
      (which ? B : A)[r * 64 + i] = s;
      if (i == 0) {
        float sb = 0.f;
        for (int d = 0; d < 512; ++d) sb = fmaf(W[r * 512 + d], fc1b[d], sb);
        (which ? kb : qb)[r] = sb;
      }
    } else {
      int id = (blk - 256) * 256 + t;
      int c = id >> 9, d = id & 511;
      float s = 0.f;
      for (int e = 0; e < 512; ++e) s = fmaf(fc2w[c * 512 + e], wv[e * 512 + d], s);
      Wc[c * 512 + d] = s;
    }
  } else if (prep_mode == 2) {
    // prep2: 34 blocks (17 G/u/w/cc + 17 ZT/tb)
    const int blk = blockIdx.x - base;
    if (blk < 17) {
      int id = blk * 256 + t;
      if (id < 4096) {
        int i = id >> 6, j = id & 63;
        float s = 0.f;
        for (int d = 0; d < 512; ++d) s = fmaf(A[d * 64 + i], B[d * 64 + j], s);
        G[i * 64 + j] = s * INVSQ;
      } else if (id < 4160) {
        int i = id - 4096; float s = 0.f;
        for (int d = 0; d < 512; ++d) s = fmaf(A[d * 64 + i], kb[d], s);
        u[i] = s * INVSQ;
      } else if (id < 4224) {
        int j = id - 4160; float s = 0.f;
        for (int d = 0; d < 512; ++d) s = fmaf(B[d * 64 + j], qb[d], s);
        w[j] = s * INVSQ;
      } else if (id == 4224) {
        float s = 0.f;
        for (int d = 0; d < 512; ++d) s = fmaf(qb[d], kb[d], s);
        cc[0] = s * INVSQ;
      }
    } else {
      int id = (blk - 17) * 256 + t;
      if (id < 4096) {
        int i = id >> 6, c = id & 63;
        float s = 0.f;
        for (int d = 0; d < 512; ++d) s = fmaf(Wc[c * 512 + d], fc1w[d * 64 + i], s);
        ZT[i * 64 + c] = s;
      } else if (id < 4160) {
        int c = id - 4096; float s = 0.f;
        for (int d = 0; d < 512; ++d) s = fmaf(Wc[c * 512 + d], fc1b[d], s);
        tb[c] = s + fc2b[c];
      }
    }
  }
}

// ---------------- bn1_final: 1 block x 256 ----------------
__global__ __launch_bounds__(256) void bn1_final_kernel(const float* __restrict__ bnp1,
                                                        const float* __restrict__ g1,
                                                        const float* __restrict__ bt1,
                                                        float* __restrict__ bn1s) {
  __shared__ float rs[4][64], rq[4][64];
  const int t = threadIdx.x, c = t & 63, g = t >> 6;
  float S = 0.f, Q = 0.f;
  for (int i = g * 128; i < g * 128 + 128; ++i) {
    S += bnp1[i * 128 + c];
    Q += bnp1[i * 128 + 64 + c];
  }
  rs[g][c] = S; rq[g][c] = Q;
  __syncthreads();
  if (t < 64) {
    float Sa = rs[0][t] + rs[1][t] + rs[2][t] + rs[3][t];
    float Qa = rq[0][t] + rq[1][t] + rq[2][t] + rq[3][t];
    float m = Sa * (1.0f / 131072.0f);
    float var = Qa * (1.0f / 131072.0f) - m * m;
    float sc = g1[t] * rsqrtf(var + EPSBN);
    bn1s[t] = sc;
    bn1s[64 + t] = bt1[t] - m * sc;
  }
}

// ---------------- fused transformer (rank-64 collapsed): 8192 blocks x 64 ----------------
__global__ __launch_bounds__(64) void transformer_fused(
    float* __restrict__ x1, const float* __restrict__ bn1s,
    const float* __restrict__ G, const float* __restrict__ u, const float* __restrict__ w,
    const float* __restrict__ cc, const float* __restrict__ ZT, const float* __restrict__ tb) {
  __shared__ float pre[16][65];
  __shared__ float ts[16][65];
  __shared__ float ys[16][65];
  __shared__ float ss[16][17];
  __shared__ float spu[16], spw[16];
  const int c = threadIdx.x;
  const size_t base = (size_t)blockIdx.x * 1024;
  const float sc = bn1s[c], sh = bn1s[64 + c];
  float pc[16];
#pragma unroll
  for (int k = 0; k < 16; ++k) {
    float v = x1[base + k * 64 + c];
    float p = fmaxf(0.f, v * sc + sh);
    pc[k] = p; pre[k][c] = p;
  }
  __syncthreads();
  float tcol[16], ycol[16];
#pragma unroll
  for (int k = 0; k < 16; ++k) { tcol[k] = 0.f; ycol[k] = 0.f; }
  for (int i = 0; i < 64; ++i) {
    float g = G[i * 64 + c];
    float z = ZT[i * 64 + c];
#pragma unroll
    for (int k = 0; k < 16; ++k) {
      float p = pre[k][i];
      tcol[k] = fmaf(p, g, tcol[k]);
      ycol[k] = fmaf(p, z, ycol[k]);
    }
  }
#pragma unroll
  for (int k = 0; k < 16; ++k) { ts[k][c] = tcol[k]; ys[k][c] = ycol[k]; }
  if (c < 16) {
    float s = 0.f;
    for (int i = 0; i < 64; ++i) s = fmaf(pre[c][i], u[i], s);
    spu[c] = s;
  } else if (c < 32) {
    int m = c - 16; float s = 0.f;
    for (int i = 0; i < 64; ++i) s = fmaf(pre[m][i], w[i], s);
    spw[m] = s;
  }
  __syncthreads();
  {
    const float cval = cc[0];
    const int m = c & 15, nb = c >> 4;
#pragma unroll
    for (int ng = 0; ng < 4; ++ng) {
      int n = ng * 4 + nb;
      float s = 0.f;
      for (int i = 0; i < 64; ++i) s = fmaf(ts[n][i], pre[m][i], s);
      ss[n][m] = s + spu[n] + spw[m] + cval;
    }
  }
  __syncthreads();
  if (c < 16) {
    float mx = -3.4e38f;
#pragma unroll
    for (int m = 0; m < 16; ++m) mx = fmaxf(mx, ss[c][m]);
    float e[16], sum = 0.f;
#pragma unroll
    for (int m = 0; m < 16; ++m) { e[m] = expf(ss[c][m] - mx); sum += e[m]; }
    float r = 1.0f / sum;
#pragma unroll
    for (int m = 0; m < 16; ++m) ss[c][m] = e[m] * r;
  }
  __syncthreads();
  const float tbc = tb[c];
  float o[16];
#pragma unroll
  for (int k = 0; k < 16; ++k) o[k] = 0.f;
#pragma unroll
  for (int m = 0; m < 16; ++m) {
    float yv = ys[m][c];
#pragma unroll
    for (int k = 0; k < 16; ++k) o[k] = fmaf(ss[k][m], yv, o[k]);
  }
#pragma unroll
  for (int k = 0; k < 16; ++k) x1[base + k * 64 + c] = o[k] + tbc + pc[k];
}

// ---------------- BN2 stats + raw pooled max (monotone BN): 1024 blocks x 256 ----------------
__global__ __launch_bounds__(256) void bn2_stats_kernel(const float* __restrict__ x2,
                                                        const float* __restrict__ w2,
                                                        const float* __restrict__ b2,
                                                        float* __restrict__ bnp2,
                                                        float* __restrict__ out) {
  __shared__ float sx2[128 * 64];
  __shared__ float ps[2][128], pq[2][128];
  const int t = threadIdx.x;
  const float4* s4 = reinterpret_cast<const float4*>(x2 + (size_t)blockIdx.x * 128 * 64);
  float4* d4 = reinterpret_cast<float4*>(sx2);
  for (int i = 0; i < 8; ++i) d4[i * 256 + t] = s4[i * 256 + t];
  __syncthreads();
  const int c = t & 127, h = t >> 7;
  float4 wreg[16];
  const float4* w4 = reinterpret_cast<const float4*>(w2 + c * 64);
#pragma unroll
  for (int i = 0; i < 16; ++i) wreg[i] = w4[i];
  const float bb = b2[c];
  float s = 0.f, q = 0.f;
  float* omax = out + 24576 + ((size_t)blockIdx.x * 8 + 4 * h) * 128 + c;
#pragma unroll
  for (int gi = 0; gi < 4; ++gi) {
    float mx = -3.4e38f;
#pragma unroll 4
    for (int p2 = 0; p2 < 16; ++p2) {
      const int p = gi * 16 + p2;
      const float4* xr = reinterpret_cast<const float4*>(&sx2[(h * 64 + p) * 64]);
      float acc = bb;
#pragma unroll
      for (int i = 0; i < 16; ++i) {
        float4 xv = xr[i];
        acc += xv.x * wreg[i].x + xv.y * wreg[i].y + xv.z * wreg[i].z + xv.w * wreg[i].w;
      }
      s += acc; q = fmaf(acc, acc, q);
      mx = fmaxf(mx, acc);
    }
    omax[(size_t)gi * 128] = mx;
  }
  ps[h][c] = s; pq[h][c] = q;
  __syncthreads();
  if (t < 128) {
    bnp2[blockIdx.x * 256 + t]       = ps[0][t] + ps[1][t];
    bnp2[blockIdx.x * 256 + 128 + t] = pq[0][t] + pq[1][t];
  }
}

// ---------------- bn2_final: 1 block x 512 ----------------
__global__ __launch_bounds__(512) void bn2_final_kernel(const float* __restrict__ bnp2,
                                                        const float* __restrict__ g2,
                                                        const float* __restrict__ bt2,
                                                        float* __restrict__ bn2s) {
  __shared__ float rs[4][128], rq[4][128];
  const int t = threadIdx.x, c = t & 127, g = t >> 7;
  float S = 0.f, Q = 0.f;
  for (int i = g * 256; i < g * 256 + 256; ++i) {
    S += bnp2[i * 256 + c];
    Q += bnp2[i * 256 + 128 + c];
  }
  rs[g][c] = S; rq[g][c] = Q;
  __syncthreads();
  if (t < 128) {
    float Sa = rs[0][t] + rs[1][t] + rs[2][t] + rs[3][t];
    float Qa = rq[0][t] + rq[1][t] + rq[2][t] + rq[3][t];
    float m = Sa * (1.0f / 131072.0f);
    float var = Qa * (1.0f / 131072.0f) - m * m;
    float sc = g2[t] * rsqrtf(var + EPSBN);
    bn2s[t] = sc;
    bn2s[128 + t] = bt2[t] - m * sc;
  }
}

// ---------------- final: in-place BN+ReLU on pooled maxes: 1024 blocks x 256 ----------------
__global__ __launch_bounds__(256) void final_kernel(const float* __restrict__ bn2s,
                                                    float* __restrict__ out) {
  __shared__ float s_sc[128], s_sh[128];
  const int t = threadIdx.x;
  if (t < 128) { s_sc[t] = bn2s[t]; s_sh[t] = bn2s[128 + t]; }
  __syncthreads();
  const int base = blockIdx.x * 1024 + t;
#pragma unroll
  for (int r = 0; r < 4; ++r) {
    const int i = base + r * 256;
    const int c = i & 127;
    float v = out[24576 + i];
    out[24576 + i] = fmaxf(0.f, v * s_sc[c] + s_sh[c]);
  }
}

// ---------------- launch ----------------
extern "C" void kernel_launch(void* const* d_in, const int* in_sizes, int n_in,
                              void* d_out, int out_size, void* d_ws, size_t ws_size,
                              hipStream_t stream) {
  const float* xyz  = (const float*)d_in[0];
  const float* feat = (const float*)d_in[1];
  const float* w1   = (const float*)d_in[2];
  const float* b1   = (const float*)d_in[3];
  const float* g1   = (const float*)d_in[4];
  const float* bt1  = (const float*)d_in[5];
  const float* fc1w = (const float*)d_in[6];
  const float* fc1b = (const float*)d_in[7];
  const float* wq   = (const float*)d_in[8];
  const float* wk   = (const float*)d_in[9];
  const float* wv   = (const float*)d_in[10];
  const float* fc2w = (const float*)d_in[11];
  const float* fc2b = (const float*)d_in[12];
  const float* w2   = (const float*)d_in[13];
  const float* b2   = (const float*)d_in[14];
  const float* g2   = (const float*)d_in[15];
  const float* bt2  = (const float*)d_in[16];
  float* out = (float*)d_out;
  char* ws = (char*)d_ws;

  int*    knn_idx = (int*)(ws + WS_KNN_IDX);
  float*  x1      = (float*)(ws + WS_X1);
  float*  bnp1    = (float*)(ws + WS_BNP1);
  float*  bn1s    = (float*)(ws + WS_BN1S);
  float*  bnp2    = (float*)(ws + WS_BNP2);
  float*  bn2s    = (float*)(ws + WS_BN2S);
  float*  Abuf    = (float*)(ws + WS_A);
  float*  Bbuf    = (float*)(ws + WS_B);
  float*  qb      = (float*)(ws + WS_QB);
  float*  kb      = (float*)(ws + WS_KB);
  float*  Wc      = (float*)(ws + WS_WC);
  float*  G       = (float*)(ws + WS_G);
  float*  ZT      = (float*)(ws + WS_ZT);
  float*  u       = (float*)(ws + WS_U);
  float*  w       = (float*)(ws + WS_W);
  float*  tb      = (float*)(ws + WS_TB);
  float*  cc      = (float*)(ws + WS_CC);
  float4* pts4    = (float4*)(ws + WS_PTS4);
  float*  fps_pd  = (float*)(ws + WS_FPSPD);
  float4* fps_c4  = (float4*)(ws + WS_FPSC4);

#define PIPE_ARGS pts4, out, fps_pd, fps_c4
#define TAIL_ARGS knn_idx, feat, w1, b1, x1, bnp1, wq, wk, fc1w, fc1b, fc2w, wv, fc2b, \
                  Abuf, Bbuf, qb, kb, Wc, G, u, w, cc, ZT, tb

  pack_kernel<<<128, 256, 0, stream>>>(xyz, pts4);
  // L1: fps[0,512) + weight combines (384)
  pipe_kernel<<<392, 256, 0, stream>>>(PIPE_ARGS, 0, -1, -1, 1, TAIL_ARGS);
  // L2: fps[512,1024) + knn[0,512) + prep2 (34)
  pipe_kernel<<<1066, 256, 0, stream>>>(PIPE_ARGS, 512, 0, -1, 2, TAIL_ARGS);
  // L3: knn[512,1024) + mlp1[0,512)
  pipe_kernel<<<1280, 256, 0, stream>>>(PIPE_ARGS, -1, 512, 0, 0, TAIL_ARGS);
  // L4: mlp1[512,1024)
  pipe_kernel<<<256, 256, 0, stream>>>(PIPE_ARGS, -1, -1, 512, 0, TAIL_ARGS);
  bn1_final_kernel<<<1, 256, 0, stream>>>(bnp1, g1, bt1, bn1s);
  transformer_fused<<<8192, 64, 0, stream>>>(x1, bn1s, G, u, w, cc, ZT, tb);
  bn2_stats_kernel<<<1024, 256, 0, stream>>>(x1, w2, b2, bnp2, out);
  bn2_final_kernel<<<1, 512, 0, stream>>>(bnp2, g2, bt2, bn2s);
  final_kernel<<<1024, 256, 0, stream>>>(bn2s, out);
#undef PIPE_ARGS
#undef TAIL_ARGS
}

// Round 18
// 1088.322 us; speedup vs baseline: 1.4205x; 1.0590x over previous
//
#include <hip/hip_runtime.h>

// ---------------- sizes ----------------
// B=8, N=4096, S=1024, K=16, C1=64, D=512, C2=128
#define EPSBN 1e-5f
#define INVSQ 0.04419417382415922f  // 1/sqrt(512)

// ---------------- ws byte offsets ----------------
#define WS_KNN_IDX   32768u       // 131072*4
#define WS_X1        1048576u     // 131072*64*4 = 33554432 (also x2 in-place)
#define WS_BNP1      34603008u    // 512*128*4
#define WS_BN1S      34865152u
#define WS_BNP2      34865664u    // 1024*256*4
#define WS_BN2S      35914240u
#define WS_A         35915264u
#define WS_B         36046336u
#define WS_QB        36177408u
#define WS_KB        36179456u
#define WS_WC        36181504u
#define WS_G         36312576u
#define WS_ZT        36328960u
#define WS_U         36345344u
#define WS_W         36345600u
#define WS_TB        36345856u
#define WS_CC        36346112u
#define WS_PTS4      36346368u    // 32768*16 = 524288
#define WS_FPSPD     36870656u    // 8*256*16*4 = 131072 (fps dist state)
#define WS_FPSC4     37001728u    // 8*16 (fps center state)

// ---------------- pack: xyz -> (x,y,z,|p|^2), 128 blocks x 256 ----------------
__global__ __launch_bounds__(256) void pack_kernel(const float* __restrict__ xyz,
                                                   float4* __restrict__ pts4) {
  int id = blockIdx.x * 256 + threadIdx.x;  // 0..32767
  float x = xyz[id * 3 + 0], y = xyz[id * 3 + 1], z = xyz[id * 3 + 2];
  float pp = __fadd_rn(__fadd_rn(__fmul_rn(x, x), __fmul_rn(y, y)), __fmul_rn(z, z));
  pts4[id] = make_float4(x, y, z, pp);
}

// ---------------- shared fps chunk body (R9-proven math, 512 iterations) ----------------
#define FPS_REDSTEP(CTRL)                                                              \
  {                                                                                    \
    unsigned lo2 = (unsigned)__builtin_amdgcn_update_dpp(0, (int)klo, CTRL, 0xF, 0xF, true); \
    unsigned hi2 = (unsigned)__builtin_amdgcn_update_dpp(0, (int)khi, CTRL, 0xF, 0xF, true); \
    bool tk = (hi2 > khi) || (hi2 == khi && lo2 > klo);                                \
    khi = tk ? hi2 : khi; klo = tk ? lo2 : klo;                                        \
  }

// smem layout for fps role: spts @0 (65536 B), cent @65536 (8192 B), red @73728 (64 B)
__device__ __forceinline__ void fps_chunk_body(unsigned char* smem, const float4* __restrict__ pts4,
                                               float* __restrict__ out_xyz,
                                               float* __restrict__ fps_pd,
                                               float4* __restrict__ fps_c4,
                                               int it0, int b, int t) {
  float4* spts = reinterpret_cast<float4*>(smem);
  float4* cent = reinterpret_cast<float4*>(smem + 65536);
  unsigned long long* red = reinterpret_cast<unsigned long long*>(smem + 73728);  // [2][4]
  const int lane = t & 63, wid = t >> 6;
  const float4* pb = pts4 + (size_t)b * 4096;
  float px[16], py[16], pz[16], pd[16];
  if (it0 == 0) {
#pragma unroll
    for (int i = 0; i < 16; ++i) {
      int j = i * 256 + t;
      float4 p = pb[j];
      spts[j] = p;
      px[i] = p.x; py[i] = p.y; pz[i] = p.z; pd[i] = 1e10f;
    }
  } else {
#pragma unroll
    for (int i = 0; i < 16; ++i) {
      int j = i * 256 + t;
      float4 p = pb[j];
      spts[j] = p;
      px[i] = p.x; py[i] = p.y; pz[i] = p.z;
      pd[i] = fps_pd[i * 2048 + b * 256 + t];
    }
  }
  __syncthreads();
  float4 c4 = (it0 == 0) ? spts[0] : fps_c4[b];
  for (int it = it0; it < it0 + 512; ++it) {
    if (t == 0) cent[it - it0] = c4;
    float bv = -1.0f; int bj = 0;
#pragma unroll
    for (int i = 0; i < 16; ++i) {
      float dx = __fsub_rn(px[i], c4.x);
      float dy = __fsub_rn(py[i], c4.y);
      float dz = __fsub_rn(pz[i], c4.z);
      float d = __fadd_rn(__fadd_rn(__fmul_rn(dx, dx), __fmul_rn(dy, dy)), __fmul_rn(dz, dz));
      float nd = fminf(pd[i], d);
      pd[i] = nd;
      bool g = nd > bv;
      bv = g ? nd : bv;
      bj = g ? (i * 256 + t) : bj;
    }
    unsigned klo = 4095u - (unsigned)bj;
    unsigned khi = __float_as_uint(bv);
    FPS_REDSTEP(0x111)
    FPS_REDSTEP(0x112)
    FPS_REDSTEP(0x114)
    FPS_REDSTEP(0x118)
    FPS_REDSTEP(0x142)
    FPS_REDSTEP(0x143)
    unsigned wlo = (unsigned)__builtin_amdgcn_readlane((int)klo, 63);
    unsigned whi = (unsigned)__builtin_amdgcn_readlane((int)khi, 63);
    const int par = it & 1;
    if (lane == 0) red[par * 4 + wid] = (((unsigned long long)whi) << 32) | wlo;
    __syncthreads();
    const ulonglong2* r2 = reinterpret_cast<const ulonglong2*>(&red[par * 4]);
    ulonglong2 ka = r2[0];
    ulonglong2 kb2 = r2[1];
    unsigned long long m0 = (ka.x > ka.y) ? ka.x : ka.y;
    unsigned long long m1 = (kb2.x > kb2.y) ? kb2.x : kb2.y;
    unsigned long long k0 = (m0 > m1) ? m0 : m1;
    int jw = 4095 - (int)(unsigned)(k0 & 0xFFFFFFFFull);
    c4 = spts[jw];
  }
  // save state (needed between chunk0 and chunk1; harmless after chunk1)
#pragma unroll
  for (int i = 0; i < 16; ++i) fps_pd[i * 2048 + b * 256 + t] = pd[i];
  if (t == 0) fps_c4[b] = c4;
  __syncthreads();
  // copy out this chunk's 512 centers
  for (int o = t; o < 1536; o += 256) {
    int j = o / 3;
    int c = o - 3 * j;
    out_xyz[(size_t)b * 3072 + (size_t)it0 * 3 + o] = (&cent[j].x)[c];
  }
}

// ---------------- kNN role body (no LDS) ----------------
__device__ __forceinline__ void knn_role_body(const float4* __restrict__ pts4,
                                              const float* __restrict__ out_xyz,
                                              int* __restrict__ knn_idx,
                                              int knn_c0, int blk, int t) {
  const int lane = t & 63;
  const int wv2 = (blk << 2) | (t >> 6);        // 0..4095
  const int b = wv2 >> 9;
  const int center = b * 1024 + knn_c0 + (wv2 & 511);
  const float4* P = pts4 + (size_t)b * 4096;
  const float cx = out_xyz[(size_t)center * 3 + 0];
  const float cy = out_xyz[(size_t)center * 3 + 1];
  const float cz = out_xyz[(size_t)center * 3 + 2];
  const float cc2 = __fadd_rn(__fadd_rn(__fmul_rn(cx, cx), __fmul_rn(cy, cy)), __fmul_rn(cz, cz));
  float ldd[16]; int ldi[16];
#pragma unroll
  for (int q = 0; q < 16; ++q) { ldd[q] = 3.4e38f; ldi[q] = 0x7fffffff; }
  for (int i = 0; i < 64; ++i) {
    int j = i * 64 + lane;
    float4 p = P[j];
    float dot = __fadd_rn(__fadd_rn(__fmul_rn(cx, p.x), __fmul_rn(cy, p.y)), __fmul_rn(cz, p.z));
    float d = __fsub_rn(__fadd_rn(cc2, p.w), __fmul_rn(2.0f, dot));
    if (d < ldd[15] || (d == ldd[15] && j < ldi[15])) {
      float cd = d; int ci = j;
#pragma unroll
      for (int q = 0; q < 16; ++q) {
        bool sw = (cd < ldd[q]) || (cd == ldd[q] && ci < ldi[q]);
        float td = ldd[q]; int ti = ldi[q];
        if (sw) { ldd[q] = cd; ldi[q] = ci; cd = td; ci = ti; }
      }
    }
  }
  float cd = ldd[0]; int ci = ldi[0];
  int* op = knn_idx + (size_t)center * 16;
#pragma unroll 1
  for (int k = 0; k < 16; ++k) {
    float wd = cd; int wi = ci;
#pragma unroll
    for (int off = 1; off < 64; off <<= 1) {
      float ov = __shfl_xor(wd, off);
      int   oi = __shfl_xor(wi, off);
      bool tk = (ov < wd) || (ov == wd && oi < wi);
      wd = tk ? ov : wd; wi = tk ? oi : wi;
    }
    if (lane == 0) op[k] = wi;
    if (wd == cd && wi == ci) {
#pragma unroll
      for (int q = 0; q < 15; ++q) { ldd[q] = ldd[q + 1]; ldi[q] = ldi[q + 1]; }
      ldd[15] = 3.4e38f; ldi[15] = 0x7fffffff;
    }
    cd = ldd[0]; ci = ldi[0];
  }
}

// ---------------- mlp1 role body (smem: w1s 16384 | b1s 256 | ls 1024 | lq 1024) ----------------
__device__ __forceinline__ void mlp1_role_body(unsigned char* smem,
                                               const float* __restrict__ feat,
                                               const float* __restrict__ w1,
                                               const float* __restrict__ b1,
                                               const int* __restrict__ knn_idx,
                                               float* __restrict__ x1, float* __restrict__ bnp1,
                                               int mlp_c0, int blk, int t) {
  float* w1s = reinterpret_cast<float*>(smem);
  float* b1s = reinterpret_cast<float*>(smem + 16384);
  float (*ls)[64] = reinterpret_cast<float(*)[64]>(smem + 16640);
  float (*lq)[64] = reinterpret_cast<float(*)[64]>(smem + 17664);
  for (int i = t; i < 4096; i += 256) w1s[i] = w1[i];
  if (t < 64) b1s[t] = b1[t];
  __syncthreads();
  const int batch = blk >> 5;
  const size_t pbase = ((size_t)batch * 1024 + mlp_c0 + (blk & 31) * 16) * 16;
  const size_t pos = pbase + t;
  const int n = knn_idx[pos];
  const float4* fp = reinterpret_cast<const float4*>(feat + ((size_t)(batch * 4096 + n)) * 64);
  float4 fr[16];
#pragma unroll
  for (int i = 0; i < 16; ++i) fr[i] = fp[i];
  float4* op = reinterpret_cast<float4*>(x1 + pos * 64);
#pragma unroll
  for (int cq = 0; cq < 16; ++cq) {
    float a0 = b1s[cq * 4 + 0], a1 = b1s[cq * 4 + 1], a2 = b1s[cq * 4 + 2], a3 = b1s[cq * 4 + 3];
#pragma unroll
    for (int iq = 0; iq < 16; ++iq) {
      float4 f4 = fr[iq];
      float4 wa = *reinterpret_cast<const float4*>(&w1s[(cq * 4 + 0) * 64 + iq * 4]);
      float4 wb = *reinterpret_cast<const float4*>(&w1s[(cq * 4 + 1) * 64 + iq * 4]);
      float4 wc = *reinterpret_cast<const float4*>(&w1s[(cq * 4 + 2) * 64 + iq * 4]);
      float4 wd = *reinterpret_cast<const float4*>(&w1s[(cq * 4 + 3) * 64 + iq * 4]);
      a0 += f4.x * wa.x + f4.y * wa.y + f4.z * wa.z + f4.w * wa.w;
      a1 += f4.x * wb.x + f4.y * wb.y + f4.z * wb.z + f4.w * wb.w;
      a2 += f4.x * wc.x + f4.y * wc.y + f4.z * wc.z + f4.w * wc.w;
      a3 += f4.x * wd.x + f4.y * wd.y + f4.z * wd.z + f4.w * wd.w;
    }
    op[cq] = make_float4(a0, a1, a2, a3);
  }
  __threadfence_block();
  __syncthreads();
  {
    const int c2 = t & 63, g = t >> 6;
    const float* p = x1 + (pbase + g * 64) * 64 + c2;
    float s = 0.f, s2 = 0.f;
    for (int i = 0; i < 64; ++i) { float v = p[(size_t)i * 64]; s += v; s2 = fmaf(v, v, s2); }
    ls[g][c2] = s; lq[g][c2] = s2;
  }
  __syncthreads();
  if (t < 64) {
    const int slot = (mlp_c0 >> 9) * 256 + blk;
    bnp1[slot * 128 + t]      = ls[0][t] + ls[1][t] + ls[2][t] + ls[3][t];
    bnp1[slot * 128 + 64 + t] = lq[0][t] + lq[1][t] + lq[2][t] + lq[3][t];
  }
}

// ---------------- big-LDS pipeline kernel (fps + hidden knn + prep) ----------------
__global__ __launch_bounds__(256) void pipe_kernel(
    const float4* __restrict__ pts4, float* __restrict__ out_xyz,
    float* __restrict__ fps_pd, float4* __restrict__ fps_c4,
    int it0, int knn_c0, int prep_mode,
    int* __restrict__ knn_idx,
    const float* __restrict__ wq, const float* __restrict__ wk,
    const float* __restrict__ fc1w, const float* __restrict__ fc1b,
    const float* __restrict__ fc2w, const float* __restrict__ wv,
    const float* __restrict__ fc2b,
    float* __restrict__ A, float* __restrict__ B,
    float* __restrict__ qb, float* __restrict__ kb, float* __restrict__ Wc,
    float* __restrict__ G, float* __restrict__ u, float* __restrict__ w,
    float* __restrict__ cc, float* __restrict__ ZT, float* __restrict__ tb) {
  __shared__ __align__(16) unsigned char smem[73792];
  const int t = threadIdx.x;
  int base = 0;
  if (it0 >= 0) {
    if (blockIdx.x < 8) {
      fps_chunk_body(smem, pts4, out_xyz, fps_pd, fps_c4, it0, blockIdx.x, t);
      return;
    }
    base = 8;
  }
  if (knn_c0 >= 0) {
    if ((int)blockIdx.x < base + 1024) {
      knn_role_body(pts4, out_xyz, knn_idx, knn_c0, blockIdx.x - base, t);
      return;
    }
    base += 1024;
  }
  // ---- prep roles ----
  if (prep_mode == 1) {
    const int blk = blockIdx.x - base;
    if (blk < 256) {
      int id = blk * 256 + t;
      int which = id >> 15;
      int rem = id & 32767;
      int r = rem >> 6, i = rem & 63;
      const float* W = which ? wk : wq;
      float s = 0.f;
      for (int d = 0; d < 512; ++d) s = fmaf(W[r * 512 + d], fc1w[d * 64 + i], s);
      (which ? B : A)[r * 64 + i] = s;
      if (i == 0) {
        float sb = 0.f;
        for (int d = 0; d < 512; ++d) sb = fmaf(W[r * 512 + d], fc1b[d], sb);
        (which ? kb : qb)[r] = sb;
      }
    } else {
      int id = (blk - 256) * 256 + t;
      int c = id >> 9, d = id & 511;
      float s = 0.f;
      for (int e = 0; e < 512; ++e) s = fmaf(fc2w[c * 512 + e], wv[e * 512 + d], s);
      Wc[c * 512 + d] = s;
    }
  } else if (prep_mode == 2) {
    const int blk = blockIdx.x - base;
    if (blk < 17) {
      int id = blk * 256 + t;
      if (id < 4096) {
        int i = id >> 6, j = id & 63;
        float s = 0.f;
        for (int d = 0; d < 512; ++d) s = fmaf(A[d * 64 + i], B[d * 64 + j], s);
        G[i * 64 + j] = s * INVSQ;
      } else if (id < 4160) {
        int i = id - 4096; float s = 0.f;
        for (int d = 0; d < 512; ++d) s = fmaf(A[d * 64 + i], kb[d], s);
        u[i] = s * INVSQ;
      } else if (id < 4224) {
        int j = id - 4160; float s = 0.f;
        for (int d = 0; d < 512; ++d) s = fmaf(B[d * 64 + j], qb[d], s);
        w[j] = s * INVSQ;
      } else if (id == 4224) {
        float s = 0.f;
        for (int d = 0; d < 512; ++d) s = fmaf(qb[d], kb[d], s);
        cc[0] = s * INVSQ;
      }
    } else {
      int id = (blk - 17) * 256 + t;
      if (id < 4096) {
        int i = id >> 6, c = id & 63;
        float s = 0.f;
        for (int d = 0; d < 512; ++d) s = fmaf(Wc[c * 512 + d], fc1w[d * 64 + i], s);
        ZT[i * 64 + c] = s;
      } else if (id < 4160) {
        int c = id - 4096; float s = 0.f;
        for (int d = 0; d < 512; ++d) s = fmaf(Wc[c * 512 + d], fc1b[d], s);
        tb[c] = s + fc2b[c];
      }
    }
  }
}

// ---------------- small-LDS tail kernel (knn at full occupancy + mlp1) ----------------
__global__ __launch_bounds__(256) void tail_kernel(
    const float4* __restrict__ pts4, const float* __restrict__ out_xyz,
    int knn_c0, int mlp_c0,
    int* __restrict__ knn_idx,
    const float* __restrict__ feat, const float* __restrict__ w1,
    const float* __restrict__ b1, float* __restrict__ x1, float* __restrict__ bnp1) {
  __shared__ __align__(16) unsigned char smem[18688];  // ~18.3 KB -> 8 blocks/CU
  const int t = threadIdx.x;
  int base = 0;
  if (knn_c0 >= 0) {
    if ((int)blockIdx.x < 1024) {
      knn_role_body(pts4, out_xyz, knn_idx, knn_c0, blockIdx.x, t);
      return;
    }
    base = 1024;
  }
  mlp1_role_body(smem, feat, w1, b1, knn_idx, x1, bnp1, mlp_c0, blockIdx.x - base, t);
}

// ---------------- bn1_final: 1 block x 256 ----------------
__global__ __launch_bounds__(256) void bn1_final_kernel(const float* __restrict__ bnp1,
                                                        const float* __restrict__ g1,
                                                        const float* __restrict__ bt1,
                                                        float* __restrict__ bn1s) {
  __shared__ float rs[4][64], rq[4][64];
  const int t = threadIdx.x, c = t & 63, g = t >> 6;
  float S = 0.f, Q = 0.f;
  for (int i = g * 128; i < g * 128 + 128; ++i) {
    S += bnp1[i * 128 + c];
    Q += bnp1[i * 128 + 64 + c];
  }
  rs[g][c] = S; rq[g][c] = Q;
  __syncthreads();
  if (t < 64) {
    float Sa = rs[0][t] + rs[1][t] + rs[2][t] + rs[3][t];
    float Qa = rq[0][t] + rq[1][t] + rq[2][t] + rq[3][t];
    float m = Sa * (1.0f / 131072.0f);
    float var = Qa * (1.0f / 131072.0f) - m * m;
    float sc = g1[t] * rsqrtf(var + EPSBN);
    bn1s[t] = sc;
    bn1s[64 + t] = bt1[t] - m * sc;
  }
}

// ---------------- fused transformer (rank-64 collapsed): 8192 blocks x 64 ----------------
__global__ __launch_bounds__(64) void transformer_fused(
    float* __restrict__ x1, const float* __restrict__ bn1s,
    const float* __restrict__ G, const float* __restrict__ u, const float* __restrict__ w,
    const float* __restrict__ cc, const float* __restrict__ ZT, const float* __restrict__ tb) {
  __shared__ float pre[16][65];
  __shared__ float ts[16][65];
  __shared__ float ys[16][65];
  __shared__ float ss[16][17];
  __shared__ float spu[16], spw[16];
  const int c = threadIdx.x;
  const size_t base = (size_t)blockIdx.x * 1024;
  const float sc = bn1s[c], sh = bn1s[64 + c];
  float pc[16];
#pragma unroll
  for (int k = 0; k < 16; ++k) {
    float v = x1[base + k * 64 + c];
    float p = fmaxf(0.f, v * sc + sh);
    pc[k] = p; pre[k][c] = p;
  }
  __syncthreads();
  float tcol[16], ycol[16];
#pragma unroll
  for (int k = 0; k < 16; ++k) { tcol[k] = 0.f; ycol[k] = 0.f; }
  for (int i = 0; i < 64; ++i) {
    float g = G[i * 64 + c];
    float z = ZT[i * 64 + c];
#pragma unroll
    for (int k = 0; k < 16; ++k) {
      float p = pre[k][i];
      tcol[k] = fmaf(p, g, tcol[k]);
      ycol[k] = fmaf(p, z, ycol[k]);
    }
  }
#pragma unroll
  for (int k = 0; k < 16; ++k) { ts[k][c] = tcol[k]; ys[k][c] = ycol[k]; }
  if (c < 16) {
    float s = 0.f;
    for (int i = 0; i < 64; ++i) s = fmaf(pre[c][i], u[i], s);
    spu[c] = s;
  } else if (c < 32) {
    int m = c - 16; float s = 0.f;
    for (int i = 0; i < 64; ++i) s = fmaf(pre[m][i], w[i], s);
    spw[m] = s;
  }
  __syncthreads();
  {
    const float cval = cc[0];
    const int m = c & 15, nb = c >> 4;
#pragma unroll
    for (int ng = 0; ng < 4; ++ng) {
      int n = ng * 4 + nb;
      float s = 0.f;
      for (int i = 0; i < 64; ++i) s = fmaf(ts[n][i], pre[m][i], s);
      ss[n][m] = s + spu[n] + spw[m] + cval;
    }
  }
  __syncthreads();
  if (c < 16) {
    float mx = -3.4e38f;
#pragma unroll
    for (int m = 0; m < 16; ++m) mx = fmaxf(mx, ss[c][m]);
    float e[16], sum = 0.f;
#pragma unroll
    for (int m = 0; m < 16; ++m) { e[m] = expf(ss[c][m] - mx); sum += e[m]; }
    float r = 1.0f / sum;
#pragma unroll
    for (int m = 0; m < 16; ++m) ss[c][m] = e[m] * r;
  }
  __syncthreads();
  const float tbc = tb[c];
  float o[16];
#pragma unroll
  for (int k = 0; k < 16; ++k) o[k] = 0.f;
#pragma unroll
  for (int m = 0; m < 16; ++m) {
    float yv = ys[m][c];
#pragma unroll
    for (int k = 0; k < 16; ++k) o[k] = fmaf(ss[k][m], yv, o[k]);
  }
#pragma unroll
  for (int k = 0; k < 16; ++k) x1[base + k * 64 + c] = o[k] + tbc + pc[k];
}

// ---------------- BN2 stats + raw pooled max (monotone BN): 1024 blocks x 256 ----------------
__global__ __launch_bounds__(256) void bn2_stats_kernel(const float* __restrict__ x2,
                                                        const float* __restrict__ w2,
                                                        const float* __restrict__ b2,
                                                        float* __restrict__ bnp2,
                                                        float* __restrict__ out) {
  __shared__ float sx2[128 * 64];
  __shared__ float ps[2][128], pq[2][128];
  const int t = threadIdx.x;
  const float4* s4 = reinterpret_cast<const float4*>(x2 + (size_t)blockIdx.x * 128 * 64);
  float4* d4 = reinterpret_cast<float4*>(sx2);
  for (int i = 0; i < 8; ++i) d4[i * 256 + t] = s4[i * 256 + t];
  __syncthreads();
  const int c = t & 127, h = t >> 7;
  float4 wreg[16];
  const float4* w4 = reinterpret_cast<const float4*>(w2 + c * 64);
#pragma unroll
  for (int i = 0; i < 16; ++i) wreg[i] = w4[i];
  const float bb = b2[c];
  float s = 0.f, q = 0.f;
  float* omax = out + 24576 + ((size_t)blockIdx.x * 8 + 4 * h) * 128 + c;
#pragma unroll
  for (int gi = 0; gi < 4; ++gi) {
    float mx = -3.4e38f;
#pragma unroll 4
    for (int p2 = 0; p2 < 16; ++p2) {
      const int p = gi * 16 + p2;
      const float4* xr = reinterpret_cast<const float4*>(&sx2[(h * 64 + p) * 64]);
      float acc = bb;
#pragma unroll
      for (int i = 0; i < 16; ++i) {
        float4 xv = xr[i];
        acc += xv.x * wreg[i].x + xv.y * wreg[i].y + xv.z * wreg[i].z + xv.w * wreg[i].w;
      }
      s += acc; q = fmaf(acc, acc, q);
      mx = fmaxf(mx, acc);
    }
    omax[(size_t)gi * 128] = mx;
  }
  ps[h][c] = s; pq[h][c] = q;
  __syncthreads();
  if (t < 128) {
    bnp2[blockIdx.x * 256 + t]       = ps[0][t] + ps[1][t];
    bnp2[blockIdx.x * 256 + 128 + t] = pq[0][t] + pq[1][t];
  }
}

// ---------------- bn2_final: 1 block x 512 ----------------
__global__ __launch_bounds__(512) void bn2_final_kernel(const float* __restrict__ bnp2,
                                                        const float* __restrict__ g2,
                                                        const float* __restrict__ bt2,
                                                        float* __restrict__ bn2s) {
  __shared__ float rs[4][128], rq[4][128];
  const int t = threadIdx.x, c = t & 127, g = t >> 7;
  float S = 0.f, Q = 0.f;
  for (int i = g * 256; i < g * 256 + 256; ++i) {
    S += bnp2[i * 256 + c];
    Q += bnp2[i * 256 + 128 + c];
  }
  rs[g][c] = S; rq[g][c] = Q;
  __syncthreads();
  if (t < 128) {
    float Sa = rs[0][t] + rs[1][t] + rs[2][t] + rs[3][t];
    float Qa = rq[0][t] + rq[1][t] + rq[2][t] + rq[3][t];
    float m = Sa * (1.0f / 131072.0f);
    float var = Qa * (1.0f / 131072.0f) - m * m;
    float sc = g2[t] * rsqrtf(var + EPSBN);
    bn2s[t] = sc;
    bn2s[128 + t] = bt2[t] - m * sc;
  }
}

// ---------------- final: in-place BN+ReLU on pooled maxes: 1024 blocks x 256 ----------------
__global__ __launch_bounds__(256) void final_kernel(const float* __restrict__ bn2s,
                                                    float* __restrict__ out) {
  __shared__ float s_sc[128], s_sh[128];
  const int t = threadIdx.x;
  if (t < 128) { s_sc[t] = bn2s[t]; s_sh[t] = bn2s[128 + t]; }
  __syncthreads();
  const int base = blockIdx.x * 1024 + t;
#pragma unroll
  for (int r = 0; r < 4; ++r) {
    const int i = base + r * 256;
    const int c = i & 127;
    float v = out[24576 + i];
    out[24576 + i] = fmaxf(0.f, v * s_sc[c] + s_sh[c]);
  }
}

// ---------------- launch ----------------
extern "C" void kernel_launch(void* const* d_in, const int* in_sizes, int n_in,
                              void* d_out, int out_size, void* d_ws, size_t ws_size,
                              hipStream_t stream) {
  const float* xyz  = (const float*)d_in[0];
  const float* feat = (const float*)d_in[1];
  const float* w1   = (const float*)d_in[2];
  const float* b1   = (const float*)d_in[3];
  const float* g1   = (const float*)d_in[4];
  const float* bt1  = (const float*)d_in[5];
  const float* fc1w = (const float*)d_in[6];
  const float* fc1b = (const float*)d_in[7];
  const float* wq   = (const float*)d_in[8];
  const float* wk   = (const float*)d_in[9];
  const float* wv   = (const float*)d_in[10];
  const float* fc2w = (const float*)d_in[11];
  const float* fc2b = (const float*)d_in[12];
  const float* w2   = (const float*)d_in[13];
  const float* b2   = (const float*)d_in[14];
  const float* g2   = (const float*)d_in[15];
  const float* bt2  = (const float*)d_in[16];
  float* out = (float*)d_out;
  char* ws = (char*)d_ws;

  int*    knn_idx = (int*)(ws + WS_KNN_IDX);
  float*  x1      = (float*)(ws + WS_X1);
  float*  bnp1    = (float*)(ws + WS_BNP1);
  float*  bn1s    = (float*)(ws + WS_BN1S);
  float*  bnp2    = (float*)(ws + WS_BNP2);
  float*  bn2s    = (float*)(ws + WS_BN2S);
  float*  Abuf    = (float*)(ws + WS_A);
  float*  Bbuf    = (float*)(ws + WS_B);
  float*  qb      = (float*)(ws + WS_QB);
  float*  kb      = (float*)(ws + WS_KB);
  float*  Wc      = (float*)(ws + WS_WC);
  float*  G       = (float*)(ws + WS_G);
  float*  ZT      = (float*)(ws + WS_ZT);
  float*  u       = (float*)(ws + WS_U);
  float*  w       = (float*)(ws + WS_W);
  float*  tb      = (float*)(ws + WS_TB);
  float*  cc      = (float*)(ws + WS_CC);
  float4* pts4    = (float4*)(ws + WS_PTS4);
  float*  fps_pd  = (float*)(ws + WS_FPSPD);
  float4* fps_c4  = (float4*)(ws + WS_FPSC4);

#define PREP_ARGS wq, wk, fc1w, fc1b, fc2w, wv, fc2b, Abuf, Bbuf, qb, kb, Wc, G, u, w, cc, ZT, tb

  pack_kernel<<<128, 256, 0, stream>>>(xyz, pts4);
  // L1: fps[0,512) + weight combines (384)
  pipe_kernel<<<392, 256, 0, stream>>>(pts4, out, fps_pd, fps_c4, 0, -1, 1,
                                       knn_idx, PREP_ARGS);
  // L2: fps[512,1024) + knn[0,512) + prep2 (34)
  pipe_kernel<<<1066, 256, 0, stream>>>(pts4, out, fps_pd, fps_c4, 512, 0, 2,
                                        knn_idx, PREP_ARGS);
  // L3: knn[512,1024) + mlp1[0,512)  (small-LDS, 8 blocks/CU)
  tail_kernel<<<1280, 256, 0, stream>>>(pts4, out, 512, 0, knn_idx, feat, w1, b1, x1, bnp1);
  // L4: mlp1[512,1024)
  tail_kernel<<<256, 256, 0, stream>>>(pts4, out, -1, 512, knn_idx, feat, w1, b1, x1, bnp1);
  bn1_final_kernel<<<1, 256, 0, stream>>>(bnp1, g1, bt1, bn1s);
  transformer_fused<<<8192, 64, 0, stream>>>(x1, bn1s, G, u, w, cc, ZT, tb);
  bn2_stats_kernel<<<1024, 256, 0, stream>>>(x1, w2, b2, bnp2, out);
  bn2_final_kernel<<<1, 512, 0, stream>>>(bnp2, g2, bt2, bn2s);
  final_kernel<<<1024, 256, 0, stream>>>(bn2s, out);
#undef PREP_ARGS
}